// Round 16
// baseline (132.070 us; speedup 1.0000x reference)
//
#include <hip/hip_runtime.h>
#include <hip/hip_bf16.h>
#include <math.h>

#define Hd   512
#define FPd  256
#define Ed   512
#define NFd  768
#define Ld   512
#define Bd   32
#define K2H  1024            // 2H
#define Nd   1024            // NF + FP
#define Md   (Ld * Bd)       // 16384

typedef _Float16 f16x8  __attribute__((ext_vector_type(8)));
typedef float    f32x4  __attribute__((ext_vector_type(4)));
typedef float    f32x16 __attribute__((ext_vector_type(16)));

// ---------------------------------------------------------------------------
// Fused prologue (one launch, 2064 blocks x 256 thr):
//  blocks [0,1024):    enc fp32 -> A16 fp16, MFMA-FRAG-MAJOR:
//     A16[(((b*8+lc)*16+c)*4+kk)*2+ms][lane][j] = fp16(enc[l][b][k]),
//     l = lc*64+ms*32+(lane&31), k = c*64+kk*16+(lane>>5)*8+j.
//     (identical frag formulas as the R13-R15 verified LDS layout)
//  blocks [1024,2048): W_big build + fp16 frag repack (R15 build_wpack)
//  blocks [2048,2064): bias_big[n] = dot(F/v row, b_feat/b_lin)
// ---------------------------------------------------------------------------
__global__ __launch_bounds__(256)
void prologue(const float* __restrict__ enc,
              const float* __restrict__ F,
              const float* __restrict__ Wf,
              const float* __restrict__ V,
              const float* __restrict__ Wl,
              const float* __restrict__ bf,
              const float* __restrict__ bl,
              _Float16* __restrict__ A16,
              _Float16* __restrict__ Bh,
              float* __restrict__ bias) {
    __shared__ float fs[32][64];
    __shared__ float wtile[32][36];
    const int bid = blockIdx.x;
    const int tid = threadIdx.x;

    if (bid < 1024) {                  // ---- enc -> A16 frag-major ----
        const int b    = bid >> 5;
        const int rem  = bid & 31;
        const int lc   = rem >> 2;
        const int q    = rem & 3;
        const int lane = tid & 63;
        const int c    = q * 4 + (tid >> 6);
        const int l31  = lane & 31;
        const int hfk  = (lane >> 5) * 8;
#pragma unroll
        for (int ms = 0; ms < 2; ms++) {
            const int l = lc * 64 + ms * 32 + l31;
            const float* src = enc + ((size_t)l * Bd + b) * K2H;
#pragma unroll
            for (int kk = 0; kk < 4; kk++) {
                const int k = c * 64 + kk * 16 + hfk;
                f32x4 p0 = *(const f32x4*)(src + k);
                f32x4 p1 = *(const f32x4*)(src + k + 4);
                f16x8 h;
                h[0] = (_Float16)p0[0]; h[1] = (_Float16)p0[1];
                h[2] = (_Float16)p0[2]; h[3] = (_Float16)p0[3];
                h[4] = (_Float16)p1[0]; h[5] = (_Float16)p1[1];
                h[6] = (_Float16)p1[2]; h[7] = (_Float16)p1[3];
                const size_t off =
                    ((((size_t)(b * 8 + lc) * 16 + c) * 4 + kk) * 2 + ms) * 512
                    + (size_t)lane * 8;
                *(f16x8*)(A16 + off) = h;
            }
        }
        return;
    }

    if (bid < 2048) {                  // ---- W_big + frag repack ----
        const int r   = bid - 1024;
        const int kx  = r & 31;
        const int ny  = r >> 5;
        const int n0  = ny * 32;
        const int kl  = tid & 31;
        const int k   = kx * 32 + kl;
        const int ty  = tid >> 5;

        const float* src;  const float* wsrc;
        if (n0 < NFd) { src = F + (size_t)n0 * Ed;          wsrc = Wf; }
        else          { src = V + (size_t)(n0 - NFd) * Hd;  wsrc = Wl; }

        float acc[4];
#pragma unroll
        for (int i = 0; i < 4; i++) acc[i] = 0.f;

        for (int e0 = 0; e0 < 512; e0 += 64) {
#pragma unroll
            for (int rep = 0; rep < 2; rep++) {
                int idx = rep * 256 + tid;
                int i   = idx >> 4;
                int kq  = idx & 15;
                float4 v4 = *(const float4*)(src + (size_t)i * 512 + e0 + kq * 4);
                *(float4*)(&fs[i][kq * 4]) = v4;
            }
            __syncthreads();
#pragma unroll 4
            for (int kk = 0; kk < 64; kk += 4) {
                float w0 = wsrc[(size_t)(e0 + kk + 0) * K2H + k];
                float w1 = wsrc[(size_t)(e0 + kk + 1) * K2H + k];
                float w2 = wsrc[(size_t)(e0 + kk + 2) * K2H + k];
                float w3 = wsrc[(size_t)(e0 + kk + 3) * K2H + k];
#pragma unroll
                for (int i = 0; i < 4; i++) {
                    float4 f4 = *(const float4*)(&fs[ty * 4 + i][kk]);
                    acc[i] += f4.x * w0 + f4.y * w1 + f4.z * w2 + f4.w * w3;
                }
            }
            __syncthreads();
        }
#pragma unroll
        for (int i = 0; i < 4; i++) wtile[ty * 4 + i][kl] = acc[i];
        __syncthreads();
        if (tid < 128) {
            const int lane = tid & 63;
            const int ksl  = tid >> 6;        // 0..1
            const int nl   = lane & 31;
            const int kf   = ksl * 16 + (lane >> 5) * 8;
            float w[8];
            *(float4*)(w)     = *(const float4*)(&wtile[nl][kf]);
            *(float4*)(w + 4) = *(const float4*)(&wtile[nl][kf + 4]);
            f16x8 h;
#pragma unroll
            for (int j = 0; j < 8; j++) h[j] = (_Float16)w[j];
            const size_t fo = ((size_t)((ny * 64) + (kx * 2 + ksl)) * 64 + lane) * 8;
            *(f16x8*)(Bh + fo) = h;
        }
        return;
    }

    {                                  // ---- bias ----
        const int n0 = (bid - 2048) * 64;
        const int ng = tid >> 2;
        const int p  = tid & 3;
        const int n  = n0 + ng;
        const float* row; const float* bsrc;
        if (n < NFd) { row = F + (size_t)n * Ed;          bsrc = bf; }
        else         { row = V + (size_t)(n - NFd) * Hd;  bsrc = bl; }
        float a = 0.f;
#pragma unroll
        for (int i = 0; i < 32; i++) {
            const int idx = i * 16 + p * 4;
            f32x4 r4 = *(const f32x4*)(row + idx);
            f32x4 s4 = *(const f32x4*)(bsrc + idx);
            a += r4[0] * s4[0] + r4[1] * s4[1] + r4[2] * s4[2] + r4[3] * s4[3];
        }
        a += __shfl_xor(a, 1);
        a += __shfl_xor(a, 2);
        if (p == 0) bias[n] = a;
    }
}

// ---------------------------------------------------------------------------
// GEMM (fp16 x fp16) + fused softmax + direct transposed store.
// Grid 256 = (b, lc): 64 rows x N=1024. 1024 thr = 16 waves.
// Wave wn: 64 rows (2 ms) x 64 cols (2 nt), acc[2][2] = 64 AGPR.
// A read DIRECTLY from frag-major A16 global (L1-resident 8KB/chunk tile,
// shared by all 16 waves) — NO LDS, NO conversion, NO barriers in K-loop;
// compiler free to software-pipeline the flat 64-iter loop.
// B frags from L2-resident Bh (2 MB). Bias folded into acc init.
// ---------------------------------------------------------------------------
__global__ __launch_bounds__(1024)
void gemm_direct(const _Float16* __restrict__ A16,
                 const _Float16* __restrict__ Bh,
                 const float* __restrict__ bias,
                 float* __restrict__ out) {
    __shared__ float red[16][64];
    __shared__ float redc[64];

    const int tid  = threadIdx.x;
    const int lane = tid & 63;
    const int wn   = tid >> 6;         // wave 0..15 -> 64-col block
    const int hf   = lane >> 5;
    const int l31  = lane & 31;
    const int b    = blockIdx.x >> 3;  // 0..31
    const int l0   = (blockIdx.x & 7) * 64;

    // bias folded into accumulator init
    float bv[2];
#pragma unroll
    for (int nt = 0; nt < 2; nt++) bv[nt] = bias[wn * 64 + nt * 32 + l31];
    f32x16 acc[2][2];
#pragma unroll
    for (int ms = 0; ms < 2; ms++)
#pragma unroll
        for (int nt = 0; nt < 2; nt++)
#pragma unroll
            for (int r = 0; r < 16; r++) acc[ms][nt][r] = bv[nt];

    const _Float16* Apl = A16 + (size_t)blockIdx.x * 65536 + (size_t)lane * 8;
    const _Float16* Bp0 = Bh + ((size_t)(wn * 2 + 0) * 4096 + lane) * 8;
    const _Float16* Bp1 = Bh + ((size_t)(wn * 2 + 1) * 4096 + lane) * 8;

#pragma unroll 2
    for (int t = 0; t < 64; ++t) {
        f16x8 a0 = *(const f16x8*)(Apl + (size_t)t * 1024);
        f16x8 a1 = *(const f16x8*)(Apl + (size_t)t * 1024 + 512);
        f16x8 b0 = *(const f16x8*)(Bp0 + (size_t)t * 512);
        f16x8 b1 = *(const f16x8*)(Bp1 + (size_t)t * 512);
        acc[0][0] = __builtin_amdgcn_mfma_f32_32x32x16_f16(a0, b0, acc[0][0], 0, 0, 0);
        acc[1][0] = __builtin_amdgcn_mfma_f32_32x32x16_f16(a1, b0, acc[1][0], 0, 0, 0);
        acc[0][1] = __builtin_amdgcn_mfma_f32_32x32x16_f16(a0, b1, acc[0][1], 0, 0, 0);
        acc[1][1] = __builtin_amdgcn_mfma_f32_32x32x16_f16(a1, b1, acc[1][1], 0, 0, 0);
    }

    // ---- epilogue: softmax over N (bias already in acc) + direct store ----
    // C/D layout: col n = lane&31, row rr = (r&3) + 8*(r>>2) + 4*hf
#pragma unroll
    for (int ms = 0; ms < 2; ms++) {
#pragma unroll
        for (int r = 0; r < 16; r++) {
            float mx = fmaxf(acc[ms][0][r], acc[ms][1][r]);
#pragma unroll
            for (int off = 1; off < 32; off <<= 1) mx = fmaxf(mx, __shfl_xor(mx, off));
            if (l31 == r) red[wn][ms * 32 + (r & 3) + 8 * (r >> 2) + 4 * hf] = mx;
        }
    }
    __syncthreads();
    if (tid < 64) {
        float v = red[0][tid];
#pragma unroll
        for (int w = 1; w < 16; w++) v = fmaxf(v, red[w][tid]);
        redc[tid] = v;
    }
    __syncthreads();

#pragma unroll
    for (int ms = 0; ms < 2; ms++) {
#pragma unroll
        for (int r = 0; r < 16; r++) {
            const int rr = ms * 32 + (r & 3) + 8 * (r >> 2) + 4 * hf;
            const float rm = redc[rr];
            float s = 0.f;
#pragma unroll
            for (int nt = 0; nt < 2; nt++) {
                float e = __expf(acc[ms][nt][r] - rm);
                acc[ms][nt][r] = e;
                s += e;
            }
#pragma unroll
            for (int off = 1; off < 32; off <<= 1) s += __shfl_xor(s, off);
            if (l31 == r) red[wn][rr] = s;
        }
    }
    __syncthreads();
    if (tid < 64) {
        float v = 0.f;
#pragma unroll
        for (int w = 0; w < 16; w++) v += red[w][tid];
        redc[tid] = 1.0f / v;
    }
    __syncthreads();

#pragma unroll
    for (int ms = 0; ms < 2; ms++) {
        float invr[16];
#pragma unroll
        for (int r = 0; r < 16; r++)
            invr[r] = redc[ms * 32 + (r & 3) + 8 * (r >> 2) + 4 * hf];
#pragma unroll
        for (int nt = 0; nt < 2; nt++) {
            const int n = wn * 64 + nt * 32 + l31;
            float* op = out + ((size_t)b * Nd + n) * Ld + l0 + ms * 32 + hf * 4;
#pragma unroll
            for (int g = 0; g < 4; g++) {
                float4 v = make_float4(acc[ms][nt][g * 4 + 0] * invr[g * 4 + 0],
                                       acc[ms][nt][g * 4 + 1] * invr[g * 4 + 1],
                                       acc[ms][nt][g * 4 + 2] * invr[g * 4 + 2],
                                       acc[ms][nt][g * 4 + 3] * invr[g * 4 + 3]);
                *(float4*)(op + 8 * g) = v;
            }
        }
    }
}

// ---------------------------------------------------------------------------
// Workspace layout (34.1 MB):
//   bias f32 [1024]    4 KB @ 0x0
//   Bh   f16 [1M]      2 MB @ 0x10000
//   A16  f16 [16M]    32 MB @ 0x210000
// ---------------------------------------------------------------------------
extern "C" void kernel_launch(void* const* d_in, const int* in_sizes, int n_in,
                              void* d_out, int out_size, void* d_ws, size_t ws_size,
                              hipStream_t stream) {
    (void)in_sizes; (void)n_in; (void)out_size; (void)ws_size;

    const float* F    = (const float*)d_in[0];   // (768, 512)
    const float* enc  = (const float*)d_in[1];   // (512, 32, 1024)
    const float* Wlin = (const float*)d_in[2];   // (512, 1024)
    const float* blin = (const float*)d_in[3];   // (512,)
    const float* Wfea = (const float*)d_in[4];   // (512, 1024)
    const float* bfea = (const float*)d_in[5];   // (512,)
    const float* V    = (const float*)d_in[6];   // (256, 512)
    float* out = (float*)d_out;                  // (32, 1024, 512)

    char* ws = (char*)d_ws;
    float*    bias = (float*)ws;                  // 4 KB
    _Float16* Bh   = (_Float16*)(ws + 0x10000);   // 2 MB
    _Float16* A16  = (_Float16*)(ws + 0x210000);  // 32 MB

    prologue<<<dim3(2064), 256, 0, stream>>>(enc, F, Wfea, V, Wlin, bfea, blin,
                                             A16, Bh, bias);
    gemm_direct<<<dim3(256), 1024, 0, stream>>>(A16, Bh, bias, out);
}

// Round 17
// 118.209 us; speedup vs baseline: 1.1173x; 1.1173x over previous
//
#include <hip/hip_runtime.h>
#include <hip/hip_bf16.h>
#include <math.h>

#define Hd   512
#define FPd  256
#define Ed   512
#define NFd  768
#define Ld   512
#define Bd   32
#define K2H  1024            // 2H
#define Nd   1024            // NF + FP
#define Md   (Ld * Bd)       // 16384

typedef _Float16 f16x8  __attribute__((ext_vector_type(8)));
typedef _Float16 f16x4  __attribute__((ext_vector_type(4)));
typedef float    f32x4  __attribute__((ext_vector_type(4)));
typedef float    f32x16 __attribute__((ext_vector_type(16)));

// ---------------------------------------------------------------------------
// Fused prologue (1040 blocks x 256 thr):
//  blocks [0,1024):    W_big build + fp16 frag repack (R15-verified)
//  blocks [1024,1040): bias_big[n] (R16-verified, 64 n per block)
// Frag layout: fo = ((ntile*64 + t)*64 + lane)*8,
//   n = ntile*32+(lane&31), k = t*16+(lane>>5)*8+j.
// ---------------------------------------------------------------------------
__global__ __launch_bounds__(256)
void prologue(const float* __restrict__ F,
              const float* __restrict__ Wf,
              const float* __restrict__ V,
              const float* __restrict__ Wl,
              const float* __restrict__ bf,
              const float* __restrict__ bl,
              _Float16* __restrict__ Bh,
              float* __restrict__ bias) {
    __shared__ float fs[32][64];
    __shared__ float wtile[32][36];
    const int bid = blockIdx.x;
    const int tid = threadIdx.x;

    if (bid < 1024) {                  // ---- W_big + frag repack ----
        const int kx  = bid & 31;
        const int ny  = bid >> 5;
        const int n0  = ny * 32;
        const int kl  = tid & 31;
        const int k   = kx * 32 + kl;
        const int ty  = tid >> 5;

        const float* src;  const float* wsrc;
        if (n0 < NFd) { src = F + (size_t)n0 * Ed;          wsrc = Wf; }
        else          { src = V + (size_t)(n0 - NFd) * Hd;  wsrc = Wl; }

        float acc[4];
#pragma unroll
        for (int i = 0; i < 4; i++) acc[i] = 0.f;

        for (int e0 = 0; e0 < 512; e0 += 64) {
#pragma unroll
            for (int rep = 0; rep < 2; rep++) {
                int idx = rep * 256 + tid;
                int i   = idx >> 4;
                int kq  = idx & 15;
                float4 v4 = *(const float4*)(src + (size_t)i * 512 + e0 + kq * 4);
                *(float4*)(&fs[i][kq * 4]) = v4;
            }
            __syncthreads();
#pragma unroll 4
            for (int kk = 0; kk < 64; kk += 4) {
                float w0 = wsrc[(size_t)(e0 + kk + 0) * K2H + k];
                float w1 = wsrc[(size_t)(e0 + kk + 1) * K2H + k];
                float w2 = wsrc[(size_t)(e0 + kk + 2) * K2H + k];
                float w3 = wsrc[(size_t)(e0 + kk + 3) * K2H + k];
#pragma unroll
                for (int i = 0; i < 4; i++) {
                    float4 f4 = *(const float4*)(&fs[ty * 4 + i][kk]);
                    acc[i] += f4.x * w0 + f4.y * w1 + f4.z * w2 + f4.w * w3;
                }
            }
            __syncthreads();
        }
#pragma unroll
        for (int i = 0; i < 4; i++) wtile[ty * 4 + i][kl] = acc[i];
        __syncthreads();
        if (tid < 128) {
            const int lane = tid & 63;
            const int ksl  = tid >> 6;        // 0..1
            const int nl   = lane & 31;
            const int kf   = ksl * 16 + (lane >> 5) * 8;
            float w[8];
            *(float4*)(w)     = *(const float4*)(&wtile[nl][kf]);
            *(float4*)(w + 4) = *(const float4*)(&wtile[nl][kf + 4]);
            f16x8 h;
#pragma unroll
            for (int j = 0; j < 8; j++) h[j] = (_Float16)w[j];
            const size_t fo = ((size_t)((ny * 64) + (kx * 2 + ksl)) * 64 + lane) * 8;
            *(f16x8*)(Bh + fo) = h;
        }
        return;
    }

    {                                  // ---- bias ----
        const int n0 = (bid - 1024) * 64;
        const int ng = tid >> 2;
        const int p  = tid & 3;
        const int n  = n0 + ng;
        const float* row; const float* bsrc;
        if (n < NFd) { row = F + (size_t)n * Ed;          bsrc = bf; }
        else         { row = V + (size_t)(n - NFd) * Hd;  bsrc = bl; }
        float a = 0.f;
#pragma unroll
        for (int i = 0; i < 32; i++) {
            const int idx = i * 16 + p * 4;
            f32x4 r4 = *(const f32x4*)(row + idx);
            f32x4 s4 = *(const f32x4*)(bsrc + idx);
            a += r4[0] * s4[0] + r4[1] * s4[1] + r4[2] * s4[2] + r4[3] * s4[3];
        }
        a += __shfl_xor(a, 1);
        a += __shfl_xor(a, 2);
        if (p == 0) bias[n] = a;
    }
}

// ---------------------------------------------------------------------------
// GEMM (fp16 x fp16) + fused softmax + direct transposed store.
// Grid 256 = (b, lc): 64 rows x N=1024. 1024 thr = 16 waves, 4/SIMD.
// Wave wn: 64 rows (2 ms) x 64 cols (2 nt), acc[2][2] = 64 AGPR.
// A: LDS frag-major conflict-free (R13: conflicts=0), 1-deep global pf.
// B: 2-DEEP register pipeline (b_cur/b_nx/b_n2; Bh padded +4KB so tail
// reads need no clamp). T5: setprio(1) around each 4-MFMA cluster.
// ---------------------------------------------------------------------------
__global__ __launch_bounds__(1024)
void gemm_direct(const float* __restrict__ enc,
                 const _Float16* __restrict__ Bh,
                 const float* __restrict__ bias,
                 float* __restrict__ out) {
    __shared__ char AsB[2][8192];      // per buf: single fp16 plane
    __shared__ float red[16][64];
    __shared__ float redc[64];

    const int tid  = threadIdx.x;
    const int lane = tid & 63;
    const int wn   = tid >> 6;         // wave 0..15 -> 64-col block
    const int hf   = lane >> 5;
    const int l31  = lane & 31;
    const int b    = blockIdx.x >> 3;  // 0..31
    const int l0   = (blockIdx.x & 7) * 64;

    // bias folded into accumulator init
    float bv[2];
#pragma unroll
    for (int nt = 0; nt < 2; nt++) bv[nt] = bias[wn * 64 + nt * 32 + l31];
    f32x16 acc[2][2];
#pragma unroll
    for (int ms = 0; ms < 2; ms++)
#pragma unroll
        for (int nt = 0; nt < 2; nt++)
#pragma unroll
            for (int r = 0; r < 16; r++) acc[ms][nt][r] = bv[nt];

    // global staging map: thread -> (row = tid>>4 in 0..63, 4 k at (tid&15)*4)
    const int srow = tid >> 4;
    const int skf  = (tid & 15) * 4;
    const float* gA = enc + ((size_t)(l0 + srow) * Bd + b) * K2H + skf;

    // LDS write target (frag-major): constant per thread
    const int kk_w   = skf >> 4;            // 0..3
    const int lh_w   = (skf & 15) >> 3;     // 0..1
    const int j0_w   = skf & 7;             // 0 or 4
    const int lane_w = lh_w * 32 + (srow & 31);
    const int slot_w = lane_w ^ ((lane_w >> 3) & 7) ^ kk_w;
    const uint32_t wb = (uint32_t)((srow >> 5) * 4096 + kk_w * 1024 + slot_w * 16 + j0_w * 2);

    // LDS read base (frag-major): per kk offset = kk*1024 + (rb16 ^ (kk<<4))
    const uint32_t rb16 = (uint32_t)((lane ^ ((lane >> 3) & 7)) << 4);

    // B fragment base pointers for this wave's two column tiles
    const _Float16* Bp0 = Bh + ((size_t)(wn * 2 + 0) * 4096 + lane) * 8;
    const _Float16* Bp1 = Bh + ((size_t)(wn * 2 + 1) * 4096 + lane) * 8;

#define STAGE_CHUNK(dst, p)                                               \
    {                                                                     \
        f16x4 h_;                                                         \
        _Pragma("unroll")                                                 \
        for (int j = 0; j < 4; j++) h_[j] = (_Float16)((p)[j]);           \
        *(f16x4*)((dst) + wb) = h_;                                       \
    }

    // prologue: stage chunk 0; preload B(t=0) and B(t=1)
    {
        f32x4 p0 = *(const f32x4*)gA;
        STAGE_CHUNK(AsB[0], p0)
    }
    f16x8 b_cur0 = *(const f16x8*)(Bp0);
    f16x8 b_cur1 = *(const f16x8*)(Bp1);
    f16x8 b_nx0  = *(const f16x8*)(Bp0 + 512);
    f16x8 b_nx1  = *(const f16x8*)(Bp1 + 512);

    for (int c = 0; c < 16; ++c) {
        __syncthreads();               // buf[c&1] staged; buf[(c+1)&1] free
        f32x4 pfA;
        if (c < 15) pfA = *(const f32x4*)(gA + (c + 1) * 64);  // 1-deep A
        const char* hbase = AsB[c & 1];
#pragma unroll
        for (int kk = 0; kk < 4; ++kk) {
            const uint32_t ko = (uint32_t)(kk * 1024) + (rb16 ^ (uint32_t)(kk << 4));
            f16x8 a0 = *(const f16x8*)(hbase + ko);
            f16x8 a1 = *(const f16x8*)(hbase + 4096 + ko);
            // issue t+2 B loads (2-deep; Bh padded so t+2<=65 is in-bounds)
            const size_t t2 = (size_t)(c * 4 + kk + 2) * 512;
            f16x8 b_n20 = *(const f16x8*)(Bp0 + t2);
            f16x8 b_n21 = *(const f16x8*)(Bp1 + t2);
            __builtin_amdgcn_s_setprio(1);
            acc[0][0] = __builtin_amdgcn_mfma_f32_32x32x16_f16(a0, b_cur0, acc[0][0], 0, 0, 0);
            acc[1][0] = __builtin_amdgcn_mfma_f32_32x32x16_f16(a1, b_cur0, acc[1][0], 0, 0, 0);
            acc[0][1] = __builtin_amdgcn_mfma_f32_32x32x16_f16(a0, b_cur1, acc[0][1], 0, 0, 0);
            acc[1][1] = __builtin_amdgcn_mfma_f32_32x32x16_f16(a1, b_cur1, acc[1][1], 0, 0, 0);
            __builtin_amdgcn_s_setprio(0);
            b_cur0 = b_nx0; b_cur1 = b_nx1;
            b_nx0 = b_n20;  b_nx1 = b_n21;
        }
        if (c < 15) STAGE_CHUNK(AsB[(c + 1) & 1], pfA)
    }

    // ---- epilogue: softmax over N (bias already in acc) + direct store ----
    // C/D layout: col n = lane&31, row rr = (r&3) + 8*(r>>2) + 4*hf
#pragma unroll
    for (int ms = 0; ms < 2; ms++) {
#pragma unroll
        for (int r = 0; r < 16; r++) {
            float mx = fmaxf(acc[ms][0][r], acc[ms][1][r]);
#pragma unroll
            for (int off = 1; off < 32; off <<= 1) mx = fmaxf(mx, __shfl_xor(mx, off));
            if (l31 == r) red[wn][ms * 32 + (r & 3) + 8 * (r >> 2) + 4 * hf] = mx;
        }
    }
    __syncthreads();
    if (tid < 64) {
        float v = red[0][tid];
#pragma unroll
        for (int w = 1; w < 16; w++) v = fmaxf(v, red[w][tid]);
        redc[tid] = v;
    }
    __syncthreads();

#pragma unroll
    for (int ms = 0; ms < 2; ms++) {
#pragma unroll
        for (int r = 0; r < 16; r++) {
            const int rr = ms * 32 + (r & 3) + 8 * (r >> 2) + 4 * hf;
            const float rm = redc[rr];
            float s = 0.f;
#pragma unroll
            for (int nt = 0; nt < 2; nt++) {
                float e = __expf(acc[ms][nt][r] - rm);
                acc[ms][nt][r] = e;
                s += e;
            }
#pragma unroll
            for (int off = 1; off < 32; off <<= 1) s += __shfl_xor(s, off);
            if (l31 == r) red[wn][rr] = s;
        }
    }
    __syncthreads();
    if (tid < 64) {
        float v = 0.f;
#pragma unroll
        for (int w = 0; w < 16; w++) v += red[w][tid];
        redc[tid] = 1.0f / v;
    }
    __syncthreads();

#pragma unroll
    for (int ms = 0; ms < 2; ms++) {
        float invr[16];
#pragma unroll
        for (int r = 0; r < 16; r++)
            invr[r] = redc[ms * 32 + (r & 3) + 8 * (r >> 2) + 4 * hf];
#pragma unroll
        for (int nt = 0; nt < 2; nt++) {
            const int n = wn * 64 + nt * 32 + l31;
            float* op = out + ((size_t)b * Nd + n) * Ld + l0 + ms * 32 + hf * 4;
#pragma unroll
            for (int g = 0; g < 4; g++) {
                float4 v = make_float4(acc[ms][nt][g * 4 + 0] * invr[g * 4 + 0],
                                       acc[ms][nt][g * 4 + 1] * invr[g * 4 + 1],
                                       acc[ms][nt][g * 4 + 2] * invr[g * 4 + 2],
                                       acc[ms][nt][g * 4 + 3] * invr[g * 4 + 3]);
                *(float4*)(op + 8 * g) = v;
            }
        }
    }
}

// ---------------------------------------------------------------------------
// Workspace layout (2.1 MB + pad):
//   bias f32 [1024]        4 KB @ 0x0
//   Bh   f16 [1M + 2K pad] 2 MB + 4 KB @ 0x10000  (pad for 2-deep tail reads)
// ---------------------------------------------------------------------------
extern "C" void kernel_launch(void* const* d_in, const int* in_sizes, int n_in,
                              void* d_out, int out_size, void* d_ws, size_t ws_size,
                              hipStream_t stream) {
    (void)in_sizes; (void)n_in; (void)out_size; (void)ws_size;

    const float* F    = (const float*)d_in[0];   // (768, 512)
    const float* enc  = (const float*)d_in[1];   // (512, 32, 1024)
    const float* Wlin = (const float*)d_in[2];   // (512, 1024)
    const float* blin = (const float*)d_in[3];   // (512,)
    const float* Wfea = (const float*)d_in[4];   // (512, 1024)
    const float* bfea = (const float*)d_in[5];   // (512,)
    const float* V    = (const float*)d_in[6];   // (256, 512)
    float* out = (float*)d_out;                  // (32, 1024, 512)

    char* ws = (char*)d_ws;
    float*    bias = (float*)ws;                  // 4 KB
    _Float16* Bh   = (_Float16*)(ws + 0x10000);   // 2 MB (+4 KB pad)

    prologue<<<dim3(1040), 256, 0, stream>>>(F, Wfea, V, Wlin, bfea, blin, Bh, bias);
    gemm_direct<<<dim3(256), 1024, 0, stream>>>(enc, Bh, bias, out);
}